// Round 5
// baseline (83.134 us; speedup 1.0000x reference)
//
#include <hip/hip_runtime.h>
#include <math.h>

// Problem constants (from reference)
#define INPUT_DIM 30000
#define UNITS     2048
#define NNZ       500000
#define BATCH     32
#define GRID_FUSED 1024

// ---------------------------------------------------------------------------
// R9: fused transpose+scatter with a MANUAL spin barrier (R6 showed fusion's
// value but cg::grid_sync costs ~50us/barrier; an atomic arrive+spin with
// threadfence release/acquire costs ~1-2us). Co-residency by construction:
// 1024 WGs x 512 thr = 8192 waves = exactly 32/CU; launch_bounds(512,8)
// forces <=64 VGPR; LDS 12.5KB << 40KB/WG at 4 WG/CU. Host occupancy query
// gates the path; falls back to the proven R8 3-kernel pipeline otherwise.
// Schedule: prefetch all cold idx/kv into regs FIRST (latency hides under
// transpose), transpose 32-col slice, spin barrier, gather+accumulate,
// LDS-reduce + fused tanh epilogue. hipMemsetAsync zeroes ws2/spill/claim/
// flag/bar (graph-capturable; also makes claim atomics race-free).
// ---------------------------------------------------------------------------
__global__ __launch_bounds__(512, 8) void fused_k(const float* __restrict__ x,
                                                  const int*   __restrict__ idx,
                                                  const float* __restrict__ kv,
                                                  const float* __restrict__ bias,
                                                  float* __restrict__ xt,
                                                  float* __restrict__ ws2,
                                                  float* __restrict__ spill,
                                                  int*   __restrict__ claim,
                                                  int*   __restrict__ flag,
                                                  int*   __restrict__ bar,
                                                  float* __restrict__ out) {
    __shared__ float tile[32][33];                // transpose staging (+1 pad)
    __shared__ float part[2 * 32 * 32];           // [rsel][es][b]  8 KB
    __shared__ int   colA[2];

    const int t    = threadIdx.x;
    const int bg   = t & 7;                       // octet covers one 128B row
    const int es   = (t >> 3) & 31;               // 0..31
    const int rsel = t >> 8;                      // 0..1
    // XCD-chunk swizzle: XCD (bid&7) owns a contiguous 256-residue range so
    // line-sharing idx/kv reads stay in one L2.
    const int wg   = ((blockIdx.x & 7) << 7) + (blockIdx.x >> 3);  // 0..1023
    const int r    = wg * 2 + rsel;               // residue 0..2047
    const int boff = bg * 4;

    // int64 vs int32 index detection (uniform): int64 LE -> high words zero.
    const bool is64 = ((idx[3] | idx[5] | idx[7]) == 0);
    const int  col0 = is64 ? idx[4 * r + 2] : idx[2 * r + 1];  // residue-uniform

    // ---- phase A: prefetch ALL 8 idx/kv entries (cold) into registers.
    // Issued before the transpose loads so both cold-miss streams are in
    // flight together; results consumed only after the barrier.
    const int base = r + UNITS * es;              // m = es + 32*j
    int   rows[8], cols[8];
    float vals[8];
    if (is64) {
        const int4* __restrict__ p = (const int4*)idx;
        #pragma unroll
        for (int j = 0; j < 8; ++j) {
            int  e  = base + j * (UNITS * 32);    // +65536 entries
            bool ok = e < NNZ;
            int4 q  = ok ? p[e] : make_int4(0, 0, col0, 0);
            rows[j] = q.x; cols[j] = q.z;
            vals[j] = ok ? kv[e] : 0.f;
        }
    } else {
        const int2* __restrict__ p = (const int2*)idx;
        #pragma unroll
        for (int j = 0; j < 8; ++j) {
            int  e  = base + j * (UNITS * 32);
            bool ok = e < NNZ;
            int2 q  = ok ? p[e] : make_int2(0, col0);
            rows[j] = q.x; cols[j] = q.y;
            vals[j] = ok ? kv[e] : 0.f;
        }
    }

    // ---- phase B: transpose 32 columns of x into xt (938 active WGs) ----
    const int i0 = blockIdx.x * 32;
    if (t < 256) {
        const int b = t >> 3;                     // batch row 0..31
        const int q = t & 7;                      // col quad 0..7
        const int i = i0 + q * 4;
        float4 v = make_float4(0.f, 0.f, 0.f, 0.f);
        if (i + 3 < INPUT_DIM) {
            v = *(const float4*)(x + (size_t)b * INPUT_DIM + i);
        } else {
            if (i + 0 < INPUT_DIM) v.x = x[(size_t)b * INPUT_DIM + i + 0];
            if (i + 1 < INPUT_DIM) v.y = x[(size_t)b * INPUT_DIM + i + 1];
            if (i + 2 < INPUT_DIM) v.z = x[(size_t)b * INPUT_DIM + i + 2];
            if (i + 3 < INPUT_DIM) v.w = x[(size_t)b * INPUT_DIM + i + 3];
        }
        tile[b][q * 4 + 0] = v.x; tile[b][q * 4 + 1] = v.y;
        tile[b][q * 4 + 2] = v.z; tile[b][q * 4 + 3] = v.w;
    }
    __syncthreads();
    if (t < 256) {
        const int il = t >> 3;                    // 0..31
        const int b4 = t & 7;                     // batch quad
        if (i0 + il < INPUT_DIM)
            ((float4*)xt)[(size_t)(i0 + il) * 8 + b4] =
                make_float4(tile[b4 * 4 + 0][il], tile[b4 * 4 + 1][il],
                            tile[b4 * 4 + 2][il], tile[b4 * 4 + 3][il]);
    }

    // ---- phase C: device-wide arrive-and-spin barrier ----
    __syncthreads();                              // all xt stores drained (vmcnt 0)
    if (t == 0) {
        __threadfence();                          // release: L2 writeback
        __hip_atomic_fetch_add(bar, 1, __ATOMIC_ACQ_REL, __HIP_MEMORY_SCOPE_AGENT);
        while (__hip_atomic_load(bar, __ATOMIC_ACQUIRE, __HIP_MEMORY_SCOPE_AGENT)
               < GRID_FUSED)
            __builtin_amdgcn_s_sleep(8);
        __threadfence();                          // acquire: invalidate stale L2
    }
    __syncthreads();

    // ---- phase D: gathers (rows already in registers) + accumulate ----
    float4 g[8];
    #pragma unroll
    for (int j = 0; j < 8; ++j)
        g[j] = *(const float4*)(xt + rows[j] * 32 + boff);
    __builtin_amdgcn_sched_barrier(0);            // keep gathers issued first

    float acc[4] = {0.f, 0.f, 0.f, 0.f};
    #pragma unroll
    for (int j = 0; j < 8; ++j) {
        float v = vals[j];
        if (cols[j] == col0) {                    // uniformly true for this data
            acc[0] += v * g[j].x; acc[1] += v * g[j].y;
            acc[2] += v * g[j].z; acc[3] += v * g[j].w;
        } else {                                  // correctness fallback
            atomicAdd(flag, 1);
            float* __restrict__ sp = spill + cols[j];
            atomicAdd(sp + (boff + 0) * UNITS, v * g[j].x);
            atomicAdd(sp + (boff + 1) * UNITS, v * g[j].y);
            atomicAdd(sp + (boff + 2) * UNITS, v * g[j].z);
            atomicAdd(sp + (boff + 3) * UNITS, v * g[j].w);
        }
    }

    // ---- phase E: combine es-stripes, claim-check, fused epilogue ----
    #pragma unroll
    for (int k = 0; k < 4; ++k)
        part[rsel * 1024 + es * 32 + boff + k] = acc[k];
    if ((t & 255) == 0) {                         // t = 0 and t = 256
        colA[rsel] = col0;
        if (atomicAdd(&claim[col0], 1) != 0) atomicAdd(flag, 1);
    }
    __syncthreads();

    if (t < 64) {
        const int rr = t >> 5;                    // rsel
        const int b  = t & 31;                    // batch row
        float s = 0.f;
        #pragma unroll
        for (int e = 0; e < 32; ++e) s += part[rr * 1024 + e * 32 + b];
        const int c = colA[rr];
        // ws2 keeps the full sum for the guard path (collisions accumulate)
        atomicAdd(&ws2[b * UNITS + c], s);
        // fused epilogue: valid whenever no spill and no collision anywhere
        out[b * UNITS + c] = tanhf(s + bias[c]);
    }
}

// ---------------------------------------------------------------------------
// Guard — early-exits on one scalar read when the fused epilogue was valid
// (flag == 0); otherwise recomputes out = tanh(ws2 + spill + bias).
// ---------------------------------------------------------------------------
__global__ __launch_bounds__(256) void guard_k(const float* __restrict__ ws2,
                                               const float* __restrict__ spill,
                                               const float* __restrict__ bias,
                                               const int* __restrict__ flag,
                                               float* __restrict__ out) {
    if (__builtin_expect(*flag == 0, 1)) return;  // clean: launch-cost only
    int tid = blockIdx.x * 256 + threadIdx.x;     // 0..65535
    int c   = tid & (UNITS - 1);
    out[tid] = tanhf(ws2[tid] + spill[tid] + bias[c]);
}

// ---------------------------------------------------------------------------
// Fallback path: proven R8 3-kernel pipeline (78.5 us) if the fused kernel
// cannot be co-resident (occupancy query < 4 blocks/CU).
// ---------------------------------------------------------------------------
__global__ __launch_bounds__(256) void transpose_k(const float* __restrict__ x,
                                                   float* __restrict__ xt,
                                                   float4* __restrict__ zero4) {
    {
        int g = blockIdx.x * 256 + threadIdx.x;
        if (g < 33281) zero4[g] = make_float4(0.f, 0.f, 0.f, 0.f);
    }
    __shared__ float tile[32][33];
    const int i0 = blockIdx.x * 32;
    const int t  = threadIdx.x;
    const int l  = t & 31;
    #pragma unroll
    for (int rep = 0; rep < 4; ++rep) {
        int b = rep * 8 + (t >> 5);
        if (i0 + l < INPUT_DIM)
            tile[b][l] = x[b * INPUT_DIM + i0 + l];
        else
            tile[b][l] = 0.f;
    }
    __syncthreads();
    const int il = t >> 3;
    const int b4 = t & 7;
    if (i0 + il < INPUT_DIM)
        ((float4*)xt)[(size_t)(i0 + il) * 8 + b4] =
            make_float4(tile[b4 * 4 + 0][il], tile[b4 * 4 + 1][il],
                        tile[b4 * 4 + 2][il], tile[b4 * 4 + 3][il]);
}

__global__ __launch_bounds__(512, 8) void scatter_k(const int* __restrict__ idx,
                                                    const float* __restrict__ kv,
                                                    const float* __restrict__ xt,
                                                    float* __restrict__ ws2,
                                                    float* __restrict__ spill,
                                                    const float* __restrict__ bias,
                                                    float* __restrict__ out,
                                                    int* __restrict__ claim,
                                                    int* __restrict__ flag) {
    __shared__ float part[64 * 32];
    __shared__ int   colA_s[1];

    const int t    = threadIdx.x;
    const int bg   = t & 7;
    const int es   = t >> 3;
    const int r    = ((blockIdx.x & 7) << 8) + (blockIdx.x >> 3);
    const int boff = bg * 4;

    const bool is64 = ((idx[3] | idx[5] | idx[7]) == 0);
    const int  col0 = is64 ? idx[4 * r + 2] : idx[2 * r + 1];

    int claimOld = 0;
    if (t == 0) { colA_s[0] = col0; claimOld = atomicAdd(&claim[col0], 1); }

    const int base = r + UNITS * es;
    int   rows[4], cols[4];
    float vals[4];
    if (is64) {
        const int4* __restrict__ p = (const int4*)idx;
        #pragma unroll
        for (int j = 0; j < 4; ++j) {
            int  e  = base + j * (UNITS * 64);
            bool ok = e < NNZ;
            int4 q  = ok ? p[e] : make_int4(0, 0, col0, 0);
            rows[j] = q.x; cols[j] = q.z;
            vals[j] = ok ? kv[e] : 0.f;
        }
    } else {
        const int2* __restrict__ p = (const int2*)idx;
        #pragma unroll
        for (int j = 0; j < 4; ++j) {
            int  e  = base + j * (UNITS * 64);
            bool ok = e < NNZ;
            int2 q  = ok ? p[e] : make_int2(0, col0);
            rows[j] = q.x; cols[j] = q.y;
            vals[j] = ok ? kv[e] : 0.f;
        }
    }

    float4 g[4];
    #pragma unroll
    for (int j = 0; j < 4; ++j)
        g[j] = *(const float4*)(xt + rows[j] * 32 + boff);
    __builtin_amdgcn_sched_barrier(0);

    float acc[4] = {0.f, 0.f, 0.f, 0.f};
    #pragma unroll
    for (int j = 0; j < 4; ++j) {
        float v = vals[j];
        if (cols[j] == col0) {
            acc[0] += v * g[j].x; acc[1] += v * g[j].y;
            acc[2] += v * g[j].z; acc[3] += v * g[j].w;
        } else {
            atomicAdd(flag, 1);
            float* __restrict__ sp = spill + cols[j];
            atomicAdd(sp + (boff + 0) * UNITS, v * g[j].x);
            atomicAdd(sp + (boff + 1) * UNITS, v * g[j].y);
            atomicAdd(sp + (boff + 2) * UNITS, v * g[j].z);
            atomicAdd(sp + (boff + 3) * UNITS, v * g[j].w);
        }
    }

    #pragma unroll
    for (int bb = 0; bb < 4; ++bb)
        part[es * 32 + boff + bb] = acc[bb];
    if (claimOld != 0) atomicAdd(flag, 1);
    __syncthreads();

    if (t < 32) {
        const int b = t;
        float s = 0.f;
        #pragma unroll
        for (int e = 0; e < 64; ++e) s += part[e * 32 + b];
        const int c = colA_s[0];
        atomicAdd(&ws2[b * UNITS + c], s);
        out[b * UNITS + c] = tanhf(s + bias[c]);
    }
}

// ---------------------------------------------------------------------------
extern "C" void kernel_launch(void* const* d_in, const int* in_sizes, int n_in,
                              void* d_out, int out_size, void* d_ws, size_t ws_size,
                              hipStream_t stream) {
    const float* x    = (const float*)d_in[0];
    const float* kv   = (const float*)d_in[1];
    const float* bias = (const float*)d_in[2];
    const int*   idx  = (const int*)d_in[3];
    float*       out  = (float*)d_out;

    // workspace: xt [960000 f] | ws2 [65536 f] | spill [65536 f] |
    //            claim [2048 i] | flag [1 i] | bar [1 i]
    float* xt    = (float*)d_ws;
    float* ws2   = xt + (size_t)INPUT_DIM * BATCH;
    float* spill = ws2 + BATCH * UNITS;
    int*   claim = (int*)(spill + BATCH * UNITS);
    int*   flag  = claim + UNITS;
    int*   bar   = flag + 1;

    // one-time co-residency check (cached): fused path needs 4 blocks/CU
    static int fusedOK = -1;
    if (fusedOK < 0) {
        int nb = 0;
        hipError_t e = hipOccupancyMaxActiveBlocksPerMultiprocessor(
            &nb, (const void*)fused_k, 512, 0);
        fusedOK = (e == hipSuccess && nb >= 4) ? 1 : 0;
    }

    // zero ws2+spill+claim+flag+bar in one small async fill (graph-capturable)
    hipMemsetAsync(ws2, 0, (size_t)(BATCH * UNITS * 2 + UNITS + 2) * sizeof(float),
                   stream);

    if (fusedOK) {
        fused_k<<<GRID_FUSED, 512, 0, stream>>>(x, idx, kv, bias, xt, ws2, spill,
                                                claim, flag, bar, out);
    } else {
        transpose_k<<<(INPUT_DIM + 31) / 32, 256, 0, stream>>>(x, xt, (float4*)ws2);
        scatter_k<<<UNITS, 512, 0, stream>>>(idx, kv, xt, ws2, spill, bias, out,
                                             claim, flag);
    }
    guard_k<<<(BATCH * UNITS) / 256, 256, 0, stream>>>(ws2, spill, bias, flag, out);
}